// Round 6
// baseline (148.586 us; speedup 1.0000x reference)
//
#include <hip/hip_runtime.h>
#include <hip/hip_bf16.h>
#include <math.h>

#define NQ   4096
#define DIMC 256
#define NHC  8
#define NPC  8
#define HDC  32
#define HC   64
#define WC   64
#define BC   4
#define KSTR 264   // full-K LDS row stride (ushorts): 528 B = 33*16 -> 2-way banks (free)

typedef __bf16 bf16x8 __attribute__((ext_vector_type(8)));
typedef __attribute__((ext_vector_type(4))) float f4;
typedef __attribute__((ext_vector_type(8))) short s8v;

__device__ __forceinline__ ushort f2bf(float f) {
  __hip_bfloat16 h = __float2bfloat16(f);
  union { __hip_bfloat16 h; ushort u; } c; c.h = h; return c.u;
}
__device__ __forceinline__ float bfu2f(ushort u) {
  union { unsigned i; float f; } c; c.i = ((unsigned)u) << 16; return c.f;
}
__device__ __forceinline__ float bflo(unsigned u) {
  union { unsigned i; float f; } c; c.i = u << 16; return c.f;
}
__device__ __forceinline__ float bfhi(unsigned u) {
  union { unsigned i; float f; } c; c.i = u & 0xffff0000u; return c.f;
}

union bfr8 { ushort u[8]; bf16x8 v; s8v s; };

// ---------------------------------------------------------------------------
// k_proj: y=0 -> loc/att projection (split-precision bf16 MFMA, 3 passes),
//         y=1 -> value projection (plain bf16 MFMA).
// Each block owns a 64-query n-tile and computes ALL output features for it:
// A (query/value) is read from HBM exactly once, staged full-K (256) in LDS,
// ONE barrier pair. B-fragments come straight from the f32 weights (L2-hot,
// <=0.5 MiB total) converted to bf16 in-register per K-step.
// ---------------------------------------------------------------------------
__global__ __launch_bounds__(256) void k_proj(
    const float* __restrict__ query, const float* __restrict__ value,
    const float* __restrict__ W_loc, const float* __restrict__ b_loc,
    const float* __restrict__ W_att, const float* __restrict__ b_att,
    const float* __restrict__ W_val, const float* __restrict__ b_val,
    float* __restrict__ loc, float* __restrict__ att,
    ushort* __restrict__ vproj) {
  __shared__ __align__(16) ushort smem[2 * 64 * KSTR];  // 67.6 KB (hi+lo)
  const int tid = threadIdx.x;
  const int b = blockIdx.z, n0 = blockIdx.x * 64;
  const int lane = tid & 63, wid = tid >> 6;
  const int am = lane & 15, kq = (lane >> 4) * 8;
  const int row4 = (lane >> 4) * 4;
  const int an = tid & 63, ak = (tid >> 6) * 8;

  if (blockIdx.y == 0) {
    // ================= loc/att: split-precision =================
    ushort* Ah = smem;
    ushort* Al = smem + 64 * KSTR;
    const float* Xb = query + (size_t)b * DIMC * NQ + n0 + an;
    for (int t = 0; t < 8; ++t) {
      const int kb = t * 32 + ak;
      float x[8];
#pragma unroll
      for (int j = 0; j < 8; ++j) x[j] = Xb[(size_t)(kb + j) * NQ];
      bfr8 ph, pl;
#pragma unroll
      for (int j = 0; j < 8; ++j) {
        ushort h = f2bf(x[j]);
        ph.u[j] = h;
        pl.u[j] = f2bf(x[j] - bfu2f(h));
      }
      *(s8v*)(&Ah[an * KSTR + kb]) = ph.s;
      *(s8v*)(&Al[an * KSTR + kb]) = pl.s;
    }
    __syncthreads();

    const int o0w = wid * 48;  // wave covers 48 output features
    const float* Wr[3];
#pragma unroll
    for (int oj = 0; oj < 3; ++oj) {
      const int o = o0w + oj * 16 + am;
      Wr[oj] = (o < 128) ? (W_loc + (size_t)o * DIMC)
                         : (W_att + (size_t)(o - 128) * DIMC);
    }
    f4 acc[4][3];
#pragma unroll
    for (int mi = 0; mi < 4; ++mi)
#pragma unroll
      for (int oj = 0; oj < 3; ++oj) acc[mi][oj] = (f4)0.f;

#pragma unroll
    for (int t = 0; t < 8; ++t) {
      const int kk = t * 32 + kq;
      bf16x8 ah[4], al[4];
#pragma unroll
      for (int mi = 0; mi < 4; ++mi) {
        ah[mi] = *(const bf16x8*)(&Ah[(mi * 16 + am) * KSTR + kk]);
        al[mi] = *(const bf16x8*)(&Al[(mi * 16 + am) * KSTR + kk]);
      }
#pragma unroll
      for (int oj = 0; oj < 3; ++oj) {
        const float4 w0 = *(const float4*)(Wr[oj] + kk);
        const float4 w1 = *(const float4*)(Wr[oj] + kk + 4);
        const float wt[8] = {w0.x, w0.y, w0.z, w0.w, w1.x, w1.y, w1.z, w1.w};
        bfr8 bh, bl;
#pragma unroll
        for (int j = 0; j < 8; ++j) {
          ushort h = f2bf(wt[j]);
          bh.u[j] = h;
          bl.u[j] = f2bf(wt[j] - bfu2f(h));
        }
#pragma unroll
        for (int mi = 0; mi < 4; ++mi) {
          acc[mi][oj] = __builtin_amdgcn_mfma_f32_16x16x32_bf16(ah[mi], bh.v, acc[mi][oj], 0, 0, 0);
          acc[mi][oj] = __builtin_amdgcn_mfma_f32_16x16x32_bf16(al[mi], bh.v, acc[mi][oj], 0, 0, 0);
          acc[mi][oj] = __builtin_amdgcn_mfma_f32_16x16x32_bf16(ah[mi], bl.v, acc[mi][oj], 0, 0, 0);
        }
      }
    }
#pragma unroll
    for (int oj = 0; oj < 3; ++oj) {
      const int oA = o0w + oj * 16;                 // 16-aligned, never straddles 128
      const bool isAtt = (oA >= 128);
      float* dstBase = isAtt ? att : loc;
      const float* bias = isAtt ? b_att : b_loc;
      const int ostride = isAtt ? 64 : 128;
      const int o = (isAtt ? oA - 128 : oA) + am;
      const float bv = bias[o];
#pragma unroll
      for (int mi = 0; mi < 4; ++mi) {
        const int nb = n0 + mi * 16 + row4;
#pragma unroll
        for (int r = 0; r < 4; ++r)
          dstBase[((size_t)b * NQ + nb + r) * ostride + o] = acc[mi][oj][r] + bv;
      }
    }
  } else {
    // ================= value projection =================
    ushort* As = smem;
    const float* Xb = value + (size_t)b * DIMC * NQ + n0 + an;
    for (int t = 0; t < 8; ++t) {
      const int kb = t * 32 + ak;
      float x[8];
#pragma unroll
      for (int j = 0; j < 8; ++j) x[j] = Xb[(size_t)(kb + j) * NQ];
      bfr8 pa;
#pragma unroll
      for (int j = 0; j < 8; ++j) pa.u[j] = f2bf(x[j]);
      *(s8v*)(&As[an * KSTR + kb]) = pa.s;
    }
    __syncthreads();

    const int o0w = wid * 64;  // wave covers 64 output features
    const float* Wr[4];
#pragma unroll
    for (int oj = 0; oj < 4; ++oj)
      Wr[oj] = W_val + (size_t)(o0w + oj * 16 + am) * DIMC;

    f4 acc[4][4];
#pragma unroll
    for (int mi = 0; mi < 4; ++mi)
#pragma unroll
      for (int oj = 0; oj < 4; ++oj) acc[mi][oj] = (f4)0.f;

#pragma unroll
    for (int t = 0; t < 8; ++t) {
      const int kk = t * 32 + kq;
      bf16x8 af[4];
#pragma unroll
      for (int mi = 0; mi < 4; ++mi)
        af[mi] = *(const bf16x8*)(&As[(mi * 16 + am) * KSTR + kk]);
#pragma unroll
      for (int oj = 0; oj < 4; ++oj) {
        const float4 w0 = *(const float4*)(Wr[oj] + kk);
        const float4 w1 = *(const float4*)(Wr[oj] + kk + 4);
        const float wt[8] = {w0.x, w0.y, w0.z, w0.w, w1.x, w1.y, w1.z, w1.w};
        bfr8 bh;
#pragma unroll
        for (int j = 0; j < 8; ++j) bh.u[j] = f2bf(wt[j]);
#pragma unroll
        for (int mi = 0; mi < 4; ++mi)
          acc[mi][oj] = __builtin_amdgcn_mfma_f32_16x16x32_bf16(af[mi], bh.v, acc[mi][oj], 0, 0, 0);
      }
    }
#pragma unroll
    for (int oj = 0; oj < 4; ++oj) {
      const int o = o0w + oj * 16 + am;
      const int h = o >> 5, d = o & 31;
      const float bias = b_val[o];
      ushort* dst = vproj + ((size_t)(b * NHC + h) * NQ) * HDC + d;
#pragma unroll
      for (int mi = 0; mi < 4; ++mi) {
        const int nb = n0 + mi * 16 + row4;
#pragma unroll
        for (int r = 0; r < 4; ++r)
          dst[(size_t)(nb + r) * HDC] = f2bf(acc[mi][oj][r] + bias);
      }
    }
  }
}

// ---------------------------------------------------------------------------
// Sampling: Phase A computes softmax + bilinear coefs once per (q,p) into
// LDS; Phase B gathers uint4 (8 bf16 channels) per corner. 64 queries/block.
// ---------------------------------------------------------------------------
__global__ __launch_bounds__(256) void k_sample(
    const float* __restrict__ loc, const float* __restrict__ attL,
    const ushort* __restrict__ vproj, ushort* __restrict__ msda) {
  __shared__ float4 Lc[64][9];
  __shared__ int4   Lo[64][9];
  const int b = blockIdx.z, h = blockIdx.y;
  const int tid = threadIdx.x;
  const int n0 = blockIdx.x * 64;
#pragma unroll
  for (int it = 0; it < 2; ++it) {
    const int idx = it * 256 + tid;
    const int q = idx >> 3, p = idx & 7;
    const int n = n0 + q;
    const float lg = attL[((size_t)b * NQ + n) * 64 + h * 8 + p];
    float m = lg;
#pragma unroll
    for (int off = 1; off < 8; off <<= 1) m = fmaxf(m, __shfl_xor(m, off, 64));
    const float e = __expf(lg - m);
    float s = e;
#pragma unroll
    for (int off = 1; off < 8; off <<= 1) s += __shfl_xor(s, off, 64);
    const float w = e / s;
    const float2 xy = *(const float2*)(loc + ((size_t)b * NQ + n) * 128 + h * 16 + p * 2);
    const float x = xy.x * 64.0f - 0.5f;
    const float y = xy.y * 64.0f - 0.5f;
    const float x0f = floorf(x), y0f = floorf(y);
    const float wx = x - x0f, wy = y - y0f;
    const int x0 = (int)x0f, y0 = (int)y0f;
    const int x1 = x0 + 1, y1 = y0 + 1;
    const float fx0 = (x0 >= 0 && x0 < WC) ? 1.f : 0.f;
    const float fx1 = (x1 >= 0 && x1 < WC) ? 1.f : 0.f;
    const float fy0 = (y0 >= 0 && y0 < HC) ? 1.f : 0.f;
    const float fy1 = (y1 >= 0 && y1 < HC) ? 1.f : 0.f;
    const int cx0 = min(max(x0, 0), WC - 1), cx1 = min(max(x1, 0), WC - 1);
    const int cy0 = min(max(y0, 0), HC - 1), cy1 = min(max(y1, 0), HC - 1);
    float4 cf;
    cf.x = w * (1.f - wx) * (1.f - wy) * fx0 * fy0;
    cf.y = w * wx * (1.f - wy) * fx1 * fy0;
    cf.z = w * (1.f - wx) * wy * fx0 * fy1;
    cf.w = w * wx * wy * fx1 * fy1;
    int4 of;
    of.x = (cy0 * WC + cx0) * HDC; of.y = (cy0 * WC + cx1) * HDC;
    of.z = (cy1 * WC + cx0) * HDC; of.w = (cy1 * WC + cx1) * HDC;
    Lc[q][p] = cf; Lo[q][p] = of;
  }
  __syncthreads();
  const int q = tid >> 2, d8 = (tid & 3) * 8;
  const int n = n0 + q;
  const ushort* vb = vproj + (size_t)((b * NHC + h) * NQ) * HDC + d8;
  float a[8] = {};
#pragma unroll
  for (int p = 0; p < 8; ++p) {
    const int4 of = Lo[q][p];
    const float4 cf = Lc[q][p];
    const uint4 u00 = *(const uint4*)(vb + of.x);
    const uint4 u01 = *(const uint4*)(vb + of.y);
    const uint4 u10 = *(const uint4*)(vb + of.z);
    const uint4 u11 = *(const uint4*)(vb + of.w);
    const unsigned c00[4] = {u00.x, u00.y, u00.z, u00.w};
    const unsigned c01[4] = {u01.x, u01.y, u01.z, u01.w};
    const unsigned c10[4] = {u10.x, u10.y, u10.z, u10.w};
    const unsigned c11[4] = {u11.x, u11.y, u11.z, u11.w};
#pragma unroll
    for (int j = 0; j < 4; ++j) {
      a[2 * j]     += cf.x * bflo(c00[j]) + cf.y * bflo(c01[j]) + cf.z * bflo(c10[j]) + cf.w * bflo(c11[j]);
      a[2 * j + 1] += cf.x * bfhi(c00[j]) + cf.y * bfhi(c01[j]) + cf.z * bfhi(c10[j]) + cf.w * bfhi(c11[j]);
    }
  }
  bfr8 r;
#pragma unroll
  for (int j = 0; j < 8; ++j) r.u[j] = f2bf(a[j]);
  *(s8v*)(msda + ((size_t)b * NQ + n) * DIMC + h * HDC + d8) = r.s;
}

// ---------------------------------------------------------------------------
// GEMM 3 (bf16 MFMA): out = msda @ W_out^T + b_out.
// Block = 64n x ALL 256 o. Full-K A staged once (no conversion, msda is
// bf16 k-contiguous), ONE barrier; B from f32 W_out (L2-hot) converted
// in-register per K-step.
// ---------------------------------------------------------------------------
__global__ __launch_bounds__(256) void k_out(
    const ushort* __restrict__ msda, const float* __restrict__ W_out,
    const float* __restrict__ b_out, float* __restrict__ out) {
  __shared__ __align__(16) ushort As[64 * KSTR];
  const int b = blockIdx.z, n0 = blockIdx.x * 64;
  const int tid = threadIdx.x, lane = tid & 63, wid = tid >> 6;
  const int am = lane & 15, kq = (lane >> 4) * 8;
  const int row4 = (lane >> 4) * 4;

  const int an = tid >> 2, akc = (tid & 3) * 64;
  const ushort* Ap = msda + ((size_t)b * NQ + n0 + an) * DIMC + akc;
  s8v av[8];
#pragma unroll
  for (int j = 0; j < 8; ++j) av[j] = *(const s8v*)(Ap + j * 8);
#pragma unroll
  for (int j = 0; j < 8; ++j) *(s8v*)(&As[an * KSTR + akc + j * 8]) = av[j];
  __syncthreads();

  const int o0w = wid * 64;
  const float* Wr[4];
#pragma unroll
  for (int oj = 0; oj < 4; ++oj)
    Wr[oj] = W_out + (size_t)(o0w + oj * 16 + am) * DIMC;

  f4 acc[4][4];
#pragma unroll
  for (int mi = 0; mi < 4; ++mi)
#pragma unroll
    for (int oj = 0; oj < 4; ++oj) acc[mi][oj] = (f4)0.f;

#pragma unroll
  for (int t = 0; t < 8; ++t) {
    const int kk = t * 32 + kq;
    bf16x8 af[4];
#pragma unroll
    for (int mi = 0; mi < 4; ++mi)
      af[mi] = *(const bf16x8*)(&As[(mi * 16 + am) * KSTR + kk]);
#pragma unroll
    for (int oj = 0; oj < 4; ++oj) {
      const float4 w0 = *(const float4*)(Wr[oj] + kk);
      const float4 w1 = *(const float4*)(Wr[oj] + kk + 4);
      const float wt[8] = {w0.x, w0.y, w0.z, w0.w, w1.x, w1.y, w1.z, w1.w};
      bfr8 bh;
#pragma unroll
      for (int j = 0; j < 8; ++j) bh.u[j] = f2bf(wt[j]);
#pragma unroll
      for (int mi = 0; mi < 4; ++mi)
        acc[mi][oj] = __builtin_amdgcn_mfma_f32_16x16x32_bf16(af[mi], bh.v, acc[mi][oj], 0, 0, 0);
    }
  }
#pragma unroll
  for (int oj = 0; oj < 4; ++oj) {
    const int o = o0w + oj * 16 + am;
    const float bias = b_out[o];
#pragma unroll
    for (int mi = 0; mi < 4; ++mi) {
      const int nb = n0 + mi * 16 + row4;
#pragma unroll
      for (int r = 0; r < 4; ++r)
        out[((size_t)b * NQ + nb + r) * DIMC + o] = acc[mi][oj][r] + bias;
    }
  }
}

extern "C" void kernel_launch(void* const* d_in, const int* in_sizes, int n_in,
                              void* d_out, int out_size, void* d_ws, size_t ws_size,
                              hipStream_t stream) {
  const float* query = (const float*)d_in[0];
  const float* value = (const float*)d_in[1];
  const float* W_loc = (const float*)d_in[2];
  const float* b_loc = (const float*)d_in[3];
  const float* W_att = (const float*)d_in[4];
  const float* b_att = (const float*)d_in[5];
  const float* W_val = (const float*)d_in[6];
  const float* b_val = (const float*)d_in[7];
  const float* W_out = (const float*)d_in[8];
  const float* b_out = (const float*)d_in[9];
  float* out = (float*)d_out;

  float* ws = (float*)d_ws;
  float* loc    = ws;                                     // 4*4096*128 f32
  float* att    = loc + (size_t)BC * NQ * 128;            // 4*4096*64 f32
  ushort* vproj = (ushort*)(att + (size_t)BC * NQ * 64);  // bf16 [b][h][n][d]
  ushort* msda  = vproj + (size_t)BC * NHC * NQ * HDC;    // bf16 [b][n][256]

  dim3 blk(256);
  k_proj  <<<dim3(NQ / 64, 2, BC), blk, 0, stream>>>(query, value, W_loc, b_loc,
             W_att, b_att, W_val, b_val, loc, att, vproj);
  k_sample<<<dim3(NQ / 64, NHC, BC), blk, 0, stream>>>(loc, att, vproj, msda);
  k_out   <<<dim3(NQ / 64, 1, BC), blk, 0, stream>>>(msda, W_out, b_out, out);
}